// Round 2
// baseline (372.548 us; speedup 1.0000x reference)
//
#include <hip/hip_runtime.h>
#include <hip/hip_bf16.h>
#include <stdint.h>
#include <stddef.h>

// out[M,N] = X[M,K] @ sign(W[N,K])^T + bias[N];  M=N=K=4096, fp32 in/out.
#define M_DIM 4096
#define N_DIM 4096
#define K_DIM 4096
#define BM 128
#define BN 128
#define BK 32
#define NKT (K_DIM / BK)   // 128

typedef __bf16 bf16;
typedef __attribute__((ext_vector_type(4))) __bf16 bf16x4;
typedef __attribute__((ext_vector_type(8))) __bf16 bf16x8;
typedef __attribute__((ext_vector_type(4))) float f32x4;

// ---------------------------------------------------------------------------
// Prep: x fp32->bf16 ; w fp32->sign(w) bf16. 16,777,216 elems each.
// Grid sized exactly: 16384 blocks x 256 threads x 1 float4 per stream.
// ---------------------------------------------------------------------------
__global__ __launch_bounds__(256) void prep_kernel(const float* __restrict__ x,
                                                   const float* __restrict__ w,
                                                   bf16* __restrict__ xb,
                                                   bf16* __restrict__ wb) {
    const int idx = blockIdx.x * 256 + threadIdx.x;   // 0 .. 4,194,303
    float4 xv = ((const float4*)x)[idx];
    bf16x4 xo;
    xo[0] = (bf16)xv.x; xo[1] = (bf16)xv.y; xo[2] = (bf16)xv.z; xo[3] = (bf16)xv.w;
    ((bf16x4*)xb)[idx] = xo;

    float4 wv = ((const float4*)w)[idx];
    bf16x4 wo;
    wo[0] = (bf16)((wv.x > 0.f) ? 1.f : ((wv.x < 0.f) ? -1.f : 0.f));
    wo[1] = (bf16)((wv.y > 0.f) ? 1.f : ((wv.y < 0.f) ? -1.f : 0.f));
    wo[2] = (bf16)((wv.z > 0.f) ? 1.f : ((wv.z < 0.f) ? -1.f : 0.f));
    wo[3] = (bf16)((wv.w > 0.f) ? 1.f : ((wv.w < 0.f) ? -1.f : 0.f));
    ((bf16x4*)wb)[idx] = wo;
}

// ---------------------------------------------------------------------------
// GEMM: 128x128 tile, 4 waves, 4x4 16x16x32 bf16 MFMAs per wave.
// Double-buffered LDS (single barrier per K-iter), global_load_lds width=16,
// XOR-swizzled granule placement to kill ds_read_b128 bank conflicts,
// supertile block rasterization for L2/L3 locality.
// ---------------------------------------------------------------------------
__device__ __forceinline__ void load_lds16(const void* g, void* l) {
    __builtin_amdgcn_global_load_lds(
        (const __attribute__((address_space(1))) void*)g,
        (__attribute__((address_space(3))) void*)l, 16, 0, 0);
}

__global__ __launch_bounds__(256) void gemm_bin_kernel(const bf16* __restrict__ A,
                                                       const bf16* __restrict__ Bw,
                                                       const float* __restrict__ bias,
                                                       float* __restrict__ C) {
    // [buf][row][slot] ; row = 32 bf16 = 64 B = 4 slots of 16 B.
    __shared__ __align__(16) bf16 As[2][BM * BK];   // 2 x 8 KB
    __shared__ __align__(16) bf16 Bs[2][BN * BK];   // 2 x 8 KB

    const int tid  = threadIdx.x;
    const int lane = tid & 63;
    const int wave = tid >> 6;
    const int wm   = wave & 1;
    const int wn   = wave >> 1;

    // Supertile rasterization: 2x2 supertiles of 16x16 blocks.
    // First dispatch generation (256 blocks) = exactly one supertile; each
    // XCD's resident blocks share 16 A-rows + 2 B-rows per K-step.
    const int pid  = blockIdx.x;
    const int supm = (pid >> 8) & 1;
    const int supn = pid >> 9;
    const int r    = pid & 255;
    const int tileM = (supm * 16 + (r >> 4)) * BM;
    const int tileN = (supn * 16 + (r & 15)) * BN;

    // --- staging (global -> LDS), swizzled granule placement --------------
    // Chunk c covers rows [c*16, c*16+16). Lane covers row c*16+(lane>>2),
    // LDS slot s = lane&3 (hardware: base + lane*16). We stage the k-granule
    // q = s ^ ((lane>>3)&3) into that slot; frag reads invert the swizzle.
    const int rowInC = lane >> 2;
    const int q_src  = (lane & 3) ^ ((lane >> 3) & 3);
    const int c0 = wave;
    const int c1 = wave + 4;

    const bf16* gA0 = A  + (size_t)(tileM + c0 * 16 + rowInC) * K_DIM + q_src * 8;
    const bf16* gA1 = A  + (size_t)(tileM + c1 * 16 + rowInC) * K_DIM + q_src * 8;
    const bf16* gB0 = Bw + (size_t)(tileN + c0 * 16 + rowInC) * K_DIM + q_src * 8;
    const bf16* gB1 = Bw + (size_t)(tileN + c1 * 16 + rowInC) * K_DIM + q_src * 8;

    f32x4 acc[4][4];
#pragma unroll
    for (int i = 0; i < 4; ++i)
#pragma unroll
        for (int j = 0; j < 4; ++j)
            acc[i][j] = (f32x4){0.f, 0.f, 0.f, 0.f};

    // Fragment read addressing (inverse swizzle):
    // lane = qf*16 + l15 wants (row = base + l15, k-granule qf) which sits at
    // slot s = qf ^ ((l15>>1)&3). Rows 0..15 for fixed qf now span all 8
    // bank-quads (2-way = free) instead of 2 (8-way).
    const int l15 = lane & 15;
    const int qf  = lane >> 4;
    const int slt = qf ^ ((l15 >> 1) & 3);
    const int fragRowA = wm * 64 + l15;
    const int fragRowB = wn * 64 + l15;
    const int fragOff  = slt * 8;   // element offset within the 32-elem row

    // Prologue: stage tile 0 into buffer 0.
    load_lds16(gA0, &As[0][c0 * 512]);
    load_lds16(gA1, &As[0][c1 * 512]);
    load_lds16(gB0, &Bs[0][c0 * 512]);
    load_lds16(gB1, &Bs[0][c1 * 512]);

    for (int kt = 0; kt < NKT; ++kt) {
        const int cur = kt & 1;
        __syncthreads();   // drains vmcnt(0): buffer `cur` staged; prior reads done

        if (kt + 1 < NKT) {
            const int nxt  = cur ^ 1;
            const size_t ko = (size_t)(kt + 1) * BK;
            load_lds16(gA0 + ko, &As[nxt][c0 * 512]);
            load_lds16(gA1 + ko, &As[nxt][c1 * 512]);
            load_lds16(gB0 + ko, &Bs[nxt][c0 * 512]);
            load_lds16(gB1 + ko, &Bs[nxt][c1 * 512]);
        }

        bf16x8 af[4], bfr[4];
#pragma unroll
        for (int i = 0; i < 4; ++i)
            af[i] = *(const bf16x8*)&As[cur][(fragRowA + i * 16) * BK + fragOff];
#pragma unroll
        for (int j = 0; j < 4; ++j)
            bfr[j] = *(const bf16x8*)&Bs[cur][(fragRowB + j * 16) * BK + fragOff];

#pragma unroll
        for (int i = 0; i < 4; ++i)
#pragma unroll
            for (int j = 0; j < 4; ++j)
                acc[i][j] = __builtin_amdgcn_mfma_f32_16x16x32_bf16(af[i], bfr[j], acc[i][j], 0, 0, 0);
        // next iteration's __syncthreads covers the write-after-read hazard:
        // buffer `nxt` reads (iteration kt-1) completed before this barrier.
    }

    // --- epilogue: C/D layout col = lane&15, row = (lane>>4)*4 + reg ------
#pragma unroll
    for (int j = 0; j < 4; ++j) {
        const int col = tileN + wn * 64 + j * 16 + l15;
        const float bv = bias[col];
#pragma unroll
        for (int i = 0; i < 4; ++i) {
            const int row0 = tileM + wm * 64 + i * 16 + (qf << 2);
#pragma unroll
            for (int rr = 0; rr < 4; ++rr) {
                C[(size_t)(row0 + rr) * N_DIM + col] = acc[i][j][rr] + bv;
            }
        }
    }
}

// ---------------------------------------------------------------------------
extern "C" void kernel_launch(void* const* d_in, const int* in_sizes, int n_in,
                              void* d_out, int out_size, void* d_ws, size_t ws_size,
                              hipStream_t stream) {
    const float* x    = (const float*)d_in[0];  // [M,K]
    const float* w    = (const float*)d_in[1];  // [N,K]
    const float* bias = (const float*)d_in[2];  // [N]
    float* out        = (float*)d_out;          // [M,N]

    const int nElem = M_DIM * K_DIM;
    bf16* xb = (bf16*)d_ws;
    bf16* wb = xb + (size_t)nElem;

    prep_kernel<<<nElem / 4 / 256, 256, 0, stream>>>(x, w, xb, wb);

    gemm_bin_kernel<<<(M_DIM / BM) * (N_DIM / BN), 256, 0, stream>>>(xb, wb, bias, out);
}

// Round 3
// 296.628 us; speedup vs baseline: 1.2559x; 1.2559x over previous
//
#include <hip/hip_runtime.h>
#include <hip/hip_bf16.h>
#include <stdint.h>
#include <stddef.h>

// out[M,N] = X[M,K] @ sign(W[N,K])^T + bias[N];  M=N=K=4096, fp32 in/out.
#define M_DIM 4096
#define N_DIM 4096
#define K_DIM 4096
#define BM 128
#define BN 128
#define BK 64
#define NKT (K_DIM / BK)   // 64

typedef __bf16 bf16;
typedef __attribute__((ext_vector_type(4))) __bf16 bf16x4;
typedef __attribute__((ext_vector_type(8))) __bf16 bf16x8;
typedef __attribute__((ext_vector_type(4))) float f32x4;

// ---------------------------------------------------------------------------
// Prep: x fp32->bf16 ; w fp32->sign(w) bf16. 16,777,216 elems each.
// ---------------------------------------------------------------------------
__global__ __launch_bounds__(256) void prep_kernel(const float* __restrict__ x,
                                                   const float* __restrict__ w,
                                                   bf16* __restrict__ xb,
                                                   bf16* __restrict__ wb) {
    const int idx = blockIdx.x * 256 + threadIdx.x;   // 0 .. 4,194,303
    float4 xv = ((const float4*)x)[idx];
    bf16x4 xo;
    xo[0] = (bf16)xv.x; xo[1] = (bf16)xv.y; xo[2] = (bf16)xv.z; xo[3] = (bf16)xv.w;
    ((bf16x4*)xb)[idx] = xo;

    float4 wv = ((const float4*)w)[idx];
    bf16x4 wo;
    wo[0] = (bf16)((wv.x > 0.f) ? 1.f : ((wv.x < 0.f) ? -1.f : 0.f));
    wo[1] = (bf16)((wv.y > 0.f) ? 1.f : ((wv.y < 0.f) ? -1.f : 0.f));
    wo[2] = (bf16)((wv.z > 0.f) ? 1.f : ((wv.z < 0.f) ? -1.f : 0.f));
    wo[3] = (bf16)((wv.w > 0.f) ? 1.f : ((wv.w < 0.f) ? -1.f : 0.f));
    ((bf16x4*)wb)[idx] = wo;
}

// ---------------------------------------------------------------------------
// GEMM: 128x128 tile, 4 waves, 4x4 16x16x32 bf16 MFMAs per wave, BK=64
// (2 K-steps per staged tile -> half the barrier drains of BK=32).
// Single-buffered LDS, 2 barriers/iter, global_load_lds width=16 staging,
// XOR-swizzled granule placement (0 bank conflicts, verified R2).
// ---------------------------------------------------------------------------
__device__ __forceinline__ void load_lds16(const void* g, void* l) {
    __builtin_amdgcn_global_load_lds(
        (const __attribute__((address_space(1))) void*)g,
        (__attribute__((address_space(3))) void*)l, 16, 0, 0);
}

__global__ __launch_bounds__(256) void gemm_bin_kernel(const bf16* __restrict__ A,
                                                       const bf16* __restrict__ Bw,
                                                       const float* __restrict__ bias,
                                                       float* __restrict__ C) {
    // Row = 64 bf16 = 128 B = 8 slots of 16 B = exactly all 32 banks.
    // Granule g of row r lives at slot s = g ^ (r&7)  (swizzle).
    __shared__ __align__(16) bf16 As[BM * BK];   // 16 KB
    __shared__ __align__(16) bf16 Bs[BN * BK];   // 16 KB

    const int tid  = threadIdx.x;
    const int lane = tid & 63;
    const int wave = tid >> 6;
    const int wm   = wave & 1;
    const int wn   = wave >> 1;

    const int tileM = blockIdx.y * BM;   // R1 raster: grid (N/BN, M/BM)
    const int tileN = blockIdx.x * BN;

    // --- staging (global -> LDS) ------------------------------------------
    // Tile = 128 rows x 64 bf16 = 16 KB = 16 chunks of 1 KB (64 lanes x 16 B).
    // Chunk c covers rows [c*8, c*8+8). Lane: row c*8 + (lane>>3),
    // LDS slot lane&7 -> must hold granule q = (lane&7) ^ (lane>>3)
    // (since row&7 = lane>>3). Wave w stages chunks w*4 .. w*4+3 of A and B.
    const int rowInC = lane >> 3;
    const int q_src  = (lane & 7) ^ rowInC;

    const bf16* gA[4];
    const bf16* gB[4];
    bf16* lA[4];
    bf16* lB[4];
#pragma unroll
    for (int t = 0; t < 4; ++t) {
        const int c = wave * 4 + t;
        gA[t] = A  + (size_t)(tileM + c * 8 + rowInC) * K_DIM + q_src * 8;
        gB[t] = Bw + (size_t)(tileN + c * 8 + rowInC) * K_DIM + q_src * 8;
        lA[t] = As + c * 512;   // 1 KB chunks (wave-uniform base)
        lB[t] = Bs + c * 512;
    }

    f32x4 acc[4][4];
#pragma unroll
    for (int i = 0; i < 4; ++i)
#pragma unroll
        for (int j = 0; j < 4; ++j)
            acc[i][j] = (f32x4){0.f, 0.f, 0.f, 0.f};

    // Fragment reads: lane = qf*16 + l15. For K-step kk (0..1), granule
    // g = kk*4 + qf; row = base + l15 (+i*16); slot s = g ^ (l15&7)
    // ((i*16 + wm*64)&7 == 0). Each 8-consecutive-lane group spans all 8
    // bank-quads -> conflict-free (R2-verified model).
    const int l15 = lane & 15;
    const int qf  = lane >> 4;
    const int fragRowA = wm * 64 + l15;
    const int fragRowB = wn * 64 + l15;

    for (int kt = 0; kt < NKT; ++kt) {
#pragma unroll
        for (int t = 0; t < 4; ++t) {
            load_lds16(gA[t], lA[t]);
            load_lds16(gB[t], lB[t]);
            gA[t] += BK; gB[t] += BK;
        }

        __syncthreads();   // drains vmcnt(0): tile staged, prior reads done

#pragma unroll
        for (int kk = 0; kk < 2; ++kk) {
            const int s = (kk * 4 + qf) ^ (l15 & 7);
            bf16x8 af[4], bfr[4];
#pragma unroll
            for (int i = 0; i < 4; ++i)
                af[i] = *(const bf16x8*)&As[(fragRowA + i * 16) * BK + s * 8];
#pragma unroll
            for (int j = 0; j < 4; ++j)
                bfr[j] = *(const bf16x8*)&Bs[(fragRowB + j * 16) * BK + s * 8];

#pragma unroll
            for (int i = 0; i < 4; ++i)
#pragma unroll
                for (int j = 0; j < 4; ++j)
                    acc[i][j] = __builtin_amdgcn_mfma_f32_16x16x32_bf16(af[i], bfr[j], acc[i][j], 0, 0, 0);
        }

        __syncthreads();   // compute done before next iter overwrites LDS
    }

    // --- epilogue: C/D layout col = lane&15, row = (lane>>4)*4 + reg ------
#pragma unroll
    for (int j = 0; j < 4; ++j) {
        const int col = tileN + wn * 64 + j * 16 + l15;
        const float bv = bias[col];
#pragma unroll
        for (int i = 0; i < 4; ++i) {
            const int row0 = tileM + wm * 64 + i * 16 + (qf << 2);
#pragma unroll
            for (int rr = 0; rr < 4; ++rr) {
                C[(size_t)(row0 + rr) * N_DIM + col] = acc[i][j][rr] + bv;
            }
        }
    }
}

// ---------------------------------------------------------------------------
extern "C" void kernel_launch(void* const* d_in, const int* in_sizes, int n_in,
                              void* d_out, int out_size, void* d_ws, size_t ws_size,
                              hipStream_t stream) {
    const float* x    = (const float*)d_in[0];  // [M,K]
    const float* w    = (const float*)d_in[1];  // [N,K]
    const float* bias = (const float*)d_in[2];  // [N]
    float* out        = (float*)d_out;          // [M,N]

    const int nElem = M_DIM * K_DIM;
    bf16* xb = (bf16*)d_ws;
    bf16* wb = xb + (size_t)nElem;

    prep_kernel<<<nElem / 4 / 256, 256, 0, stream>>>(x, w, xb, wb);

    dim3 grid(N_DIM / BN, M_DIM / BM);          // 32 x 32
    gemm_bin_kernel<<<grid, 256, 0, stream>>>(xb, wb, bias, out);
}